// Round 6
// baseline (1232.870 us; speedup 1.0000x reference)
//
#include <hip/hip_runtime.h>
#include <hip/hip_bf16.h>
#include <cstdint>
#include <cstddef>

// ---------------------------------------------------------------------------
// Swin window attention, fused: qkv GEMM -> per-head attention -> proj GEMM.
// One block per window (4096 blocks, 512 threads = 8 waves). bf16 MFMA
// 16x16x32, fp32 accumulate. DYNAMIC LDS (148.5/158.3 KB) passed at launch;
// hipFuncSetAttribute(MaxDynamicSharedMemorySize) raised first in case the
// runtime enforces the 64 KB default cap (error-ignored, idempotent,
// graph-capture-safe: host-side, not stream-ordered, no alloc/sync).
//   - Weights pre-swizzled to exact MFMA B-fragment order in d_ws (bf16).
//   - Relative-position-bias + mask pre-fused into one bf16 table cbm[w][h][o]
//     in d_ws (read from global; L1/L2-resident, 4.8 KB per (window,head)).
//   - qkv kk-loop software-pipelined depth-1: A-frags (LDS) and B-frags
//     (global) for kk+1 prefetched before kk's MFMAs issue (2 waves/SIMD
//     resident -> ILP must hide the ~120/200-cyc load latency).
//   - cbm adds and proj B-frags hoisted above the MFMAs preceding their use.
//   - Softmax without max-subtraction (scores O(1) by construction; softmax
//     shift-invariant; masked/padded entries exp to 0; no-overflow audited).
//   - lps (P matrix) wave-private (writer wave == PV reader wave per row)
//     -> no barrier. loh double-buffered on p&1 -> one barrier per pass.
//     10 barriers total per block.
// Fallback tiers if ws is too small: weights-only prepack, or fully direct.
// ---------------------------------------------------------------------------

typedef __attribute__((ext_vector_type(4))) float f32x4;
typedef __attribute__((ext_vector_type(8))) short s16x8;
typedef __attribute__((ext_vector_type(4))) ushort u16x4;

#define NTOK   49
#define DIM_   384
#define NHEAD  12
#define MROWS  64          // 49 rows padded to 4 M-tiles of 16

// LDS strides (ushort elements). Start-bank spread for b128 column reads:
// XS 784B/row -> 2-way (free, m136); QK/OH 80B -> 2-way; VT/PS 144B -> 2-way.
#define XS_STR 392         // 384 + 8 pad
#define QK_STR 40          // 32 + 8 pad
#define VT_STR 72          // 64 + 8 pad
#define PS_STR 72
#define OH_STR 40

// dynamic-LDS byte offsets (all 16-aligned)
#define OFF_XS   0
#define OFF_Q    (OFF_XS + MROWS*XS_STR*2)            // 50176
#define OFF_K    (OFF_Q  + 4*MROWS*QK_STR*2)          // 70656
#define OFF_VT   (OFF_K  + 4*MROWS*QK_STR*2)          // 91136
#define OFF_PS   (OFF_VT + 4*32*VT_STR*2)             // 109568
#define OFF_OH   (OFF_PS + 2*MROWS*PS_STR*2)          // 128000 ([2buf][2wg][64][OH_STR])
#define OFF_MASK (OFF_OH + 2*2*MROWS*OH_STR*2)        // 148480
#define OFF_BT   (OFF_MASK + 4804)
#define OFF_IDX  (OFF_BT + 169*12*2)
#define SMEM_SMALL (OFF_MASK)                          // 148480 (PREC path)
#define SMEM_BIG   (((OFF_IDX + 2401*2) + 15) & ~15)   // 162144 (< 163840)

#define QKV_PRE_ELEMS  (12*72*64*8)     // 442368 bf16
#define PROJ_PRE_ELEMS (12*24*64*8)     // 147456 bf16
#define CBM_ELEMS      (64*12*2401)     // 1843968 bf16
#define WS_W    ((size_t)(QKV_PRE_ELEMS + PROJ_PRE_ELEMS) * 2)
#define WS_FULL (WS_W + (size_t)CBM_ELEMS * 2)

static __device__ __forceinline__ ushort f2bf(float f){
    union { float f; uint32_t u; } v; v.f = f;
    uint32_t r = (v.u + 0x7FFFu + ((v.u >> 16) & 1u)) >> 16;   // RNE
    return (ushort)r;
}
static __device__ __forceinline__ float bf2f(ushort b){
    union { uint32_t u; float f; } v; v.u = ((uint32_t)b) << 16;
    return v.f;
}

// Pre-swizzle weights into exact MFMA B-fragment order:
// frag element (kk, ct, lane, i)  <-  W[kk*32 + (lane>>4)*8 + i][ct*16 + (lane&15)]
__global__ void prep_weights(const float* __restrict__ qkv_w,
                             const float* __restrict__ proj_w,
                             ushort* __restrict__ wq,
                             ushort* __restrict__ wp)
{
    int e = blockIdx.x * 256 + threadIdx.x;
    if (e < QKV_PRE_ELEMS){
        int i = e & 7, lane = (e >> 3) & 63, rest = e >> 9;
        int ct = rest % 72, kk = rest / 72;
        int row = kk*32 + (lane >> 4)*8 + i;
        int col = ct*16 + (lane & 15);
        wq[e] = f2bf(qkv_w[(size_t)row * 1152 + col]);
    } else if (e < QKV_PRE_ELEMS + PROJ_PRE_ELEMS){
        int e2 = e - QKV_PRE_ELEMS;
        int i = e2 & 7, lane = (e2 >> 3) & 63, rest = e2 >> 9;
        int ct = rest % 24, kk = rest / 24;
        int row = kk*32 + (lane >> 4)*8 + i;
        int col = ct*16 + (lane & 15);
        wp[e2] = f2bf(proj_w[(size_t)row * 384 + col]);
    }
}

// Pre-fuse relative-position bias gather + window mask:
// cbm[w][h][o] = mask[w][o] + bias_table[rel_index[o]][h], bf16.
__global__ void prep_cbm(const float* __restrict__ mask,
                         const float* __restrict__ bias_table,
                         const int*   __restrict__ rel_index,
                         ushort* __restrict__ cbm)
{
    int e = blockIdx.x * 256 + threadIdx.x;
    if (e < CBM_ELEMS){
        int o = e % 2401;
        int rem = e / 2401;
        int h = rem % 12, w = rem / 12;
        cbm[e] = f2bf(mask[(size_t)w*2401 + o] + bias_table[rel_index[o]*12 + h]);
    }
}

template<bool PREW>
static __device__ __forceinline__ s16x8 load_qkvw(const ushort* __restrict__ wq_pre,
                                                  const float* __restrict__ qkv_w,
                                                  int kk, int ct, int colbase,
                                                  int lane, int lg, int l15)
{
    if (PREW){
        return *(const s16x8*)(wq_pre + ((size_t)(kk*72 + ct)*64 + lane)*8);
    } else {
        s16x8 bw;
        #pragma unroll
        for (int i = 0; i < 8; ++i)
            bw[i] = (short)f2bf(qkv_w[(size_t)(kk*32 + lg*8 + i)*1152 + colbase + l15]);
        return bw;
    }
}

template<bool PREW, bool PREC>
__global__ __launch_bounds__(512, 2)
void win_attn_kernel(const float* __restrict__ x,
                     const float* __restrict__ mask,
                     const float* __restrict__ qkv_b,
                     const float* __restrict__ bias_table,
                     const int*   __restrict__ rel_index,
                     const float* __restrict__ proj_b,
                     const ushort* __restrict__ wq_pre,
                     const ushort* __restrict__ wp_pre,
                     const ushort* __restrict__ cbm,
                     const float* __restrict__ qkv_w,
                     const float* __restrict__ proj_w,
                     float* __restrict__ out)
{
    extern __shared__ __align__(16) char smem[];
    ushort* lxs  = (ushort*)(smem + OFF_XS);   // x bf16 [64][XS_STR]
    ushort* lq   = (ushort*)(smem + OFF_Q);    // q [4][64][QK_STR]
    ushort* lk   = (ushort*)(smem + OFF_K);    // k [4][64][QK_STR]
    ushort* lvt  = (ushort*)(smem + OFF_VT);   // v^T [4][32][VT_STR]
    ushort* lps  = (ushort*)(smem + OFF_PS);   // P [2wg][64][PS_STR] (wave-private)
    ushort* loh  = (ushort*)(smem + OFF_OH);   // head-out [2buf][2wg][64][OH_STR]
    ushort* lmask= (ushort*)(smem + OFF_MASK); // only allocated when !PREC
    ushort* lbt  = (ushort*)(smem + OFF_BT);
    ushort* lidx = (ushort*)(smem + OFF_IDX);

    const int tid  = threadIdx.x;
    const int wave = tid >> 6;
    const int lane = tid & 63;
    const int l15  = lane & 15;
    const int lg   = lane >> 4;
    const int b    = blockIdx.x;

    // ---- stage x (bf16, rows >=49 zeroed); mask/bt/idx only if !PREC
    {
        const float4* xb = (const float4*)(x + (size_t)b * (NTOK*DIM_));
        for (int e = tid; e < MROWS*96; e += 512){
            int row = e / 96, c4 = e - row*96;
            float4 v;
            if (row < NTOK) v = xb[row*96 + c4];
            else { v.x = v.y = v.z = v.w = 0.f; }
            uint2 pk;
            pk.x = (uint32_t)f2bf(v.x) | ((uint32_t)f2bf(v.y) << 16);
            pk.y = (uint32_t)f2bf(v.z) | ((uint32_t)f2bf(v.w) << 16);
            *(uint2*)(lxs + row*XS_STR + c4*4) = pk;
        }
        if (!PREC){
            const float* mb = mask + (size_t)(b & 63) * 2401;
            for (int e = tid; e < 2401; e += 512) lmask[e] = f2bf(mb[e]);
            for (int e = tid; e < 169*12; e += 512) lbt[e] = f2bf(bias_table[e]);
            for (int e = tid; e < 2401; e += 512) lidx[e] = (ushort)rel_index[e];
        }
    }
    __syncthreads();

    const f32x4 zf = {0.f, 0.f, 0.f, 0.f};
    // proj accumulator: wave owns output cols [wave*48, wave*48+48)
    f32x4 oacc[4][3];
    #pragma unroll
    for (int m = 0; m < 4; ++m)
        #pragma unroll
        for (int n = 0; n < 3; ++n) oacc[m][n] = zf;

    #pragma unroll 1
    for (int g = 0; g < 3; ++g){
        const int h0 = g * 4;

        // ---- qkv: 24 tasks (head, q/k/v, ntile), 3 per wave, kk-outer,
        //      depth-1 software pipeline on both A (LDS) and B (global) frags.
        int which_[3], hh_[3], nt_[3], colbase_[3], ct_[3];
        #pragma unroll
        for (int tt = 0; tt < 3; ++tt){
            int t = wave*3 + tt;
            int hh = t / 6;
            int rem = t - hh*6;
            int which = rem >> 1, nt = rem & 1;
            which_[tt] = which; hh_[tt] = hh; nt_[tt] = nt;
            colbase_[tt] = which*384 + (h0 + hh)*32 + nt*16;
            ct_[tt] = which*24 + (h0 + hh)*2 + nt;
        }
        f32x4 acc[3][4];
        #pragma unroll
        for (int tt = 0; tt < 3; ++tt)
            #pragma unroll
            for (int m = 0; m < 4; ++m) acc[tt][m] = zf;

        s16x8 aC[4], bC[3];
        #pragma unroll
        for (int m = 0; m < 4; ++m)
            aC[m] = *(const s16x8*)(lxs + (m*16 + l15)*XS_STR + lg*8);
        #pragma unroll
        for (int tt = 0; tt < 3; ++tt)
            bC[tt] = load_qkvw<PREW>(wq_pre, qkv_w, 0, ct_[tt], colbase_[tt], lane, lg, l15);

        #pragma unroll
        for (int kk = 0; kk < 12; ++kk){
            s16x8 aN[4], bN[3];
            if (kk < 11){
                #pragma unroll
                for (int m = 0; m < 4; ++m)
                    aN[m] = *(const s16x8*)(lxs + (m*16 + l15)*XS_STR + (kk+1)*32 + lg*8);
                #pragma unroll
                for (int tt = 0; tt < 3; ++tt)
                    bN[tt] = load_qkvw<PREW>(wq_pre, qkv_w, kk+1, ct_[tt], colbase_[tt], lane, lg, l15);
            }
            #pragma unroll
            for (int tt = 0; tt < 3; ++tt)
                #pragma unroll
                for (int m = 0; m < 4; ++m)
                    acc[tt][m] = __builtin_amdgcn_mfma_f32_16x16x32_bf16(aC[m], bC[tt], acc[tt][m], 0, 0, 0);
            if (kk < 11){
                #pragma unroll
                for (int m = 0; m < 4; ++m) aC[m] = aN[m];
                #pragma unroll
                for (int tt = 0; tt < 3; ++tt) bC[tt] = bN[tt];
            }
        }
        #pragma unroll
        for (int tt = 0; tt < 3; ++tt){
            const float bias = qkv_b[colbase_[tt] + l15];
            const int hh = hh_[tt], nt = nt_[tt], which = which_[tt];
            if (which == 0){
                #pragma unroll
                for (int m = 0; m < 4; ++m)
                    #pragma unroll
                    for (int i = 0; i < 4; ++i){
                        int r = m*16 + lg*4 + i;
                        lq[(hh*MROWS + r)*QK_STR + nt*16 + l15] =
                            f2bf((acc[tt][m][i] + bias) * 0.17677669529663689f);
                    }
            } else if (which == 1){
                #pragma unroll
                for (int m = 0; m < 4; ++m)
                    #pragma unroll
                    for (int i = 0; i < 4; ++i){
                        int r = m*16 + lg*4 + i;
                        lk[(hh*MROWS + r)*QK_STR + nt*16 + l15] = f2bf(acc[tt][m][i] + bias);
                    }
            } else {   // v stored transposed: vT[head-col][token]; i consecutive
                #pragma unroll
                for (int m = 0; m < 4; ++m){
                    u16x4 pk;
                    #pragma unroll
                    for (int i = 0; i < 4; ++i) pk[i] = f2bf(acc[tt][m][i] + bias);
                    *(u16x4*)(lvt + (hh*32 + nt*16 + l15)*VT_STR + m*16 + lg*4) = pk;
                }
            }
        }
        __syncthreads();

        // ---- attention + proj, two heads per pass
        #pragma unroll 1
        for (int p = 0; p < 2; ++p){
            const int wg = wave >> 2;      // head of the pair
            const int mt = wave & 3;       // M-tile owned
            const int hh = 2*p + wg;
            const int h  = h0 + hh;

            // Hoist additive bias+mask terms (independent of the MFMAs below,
            // ~200-cyc global loads hide under QK^T + softmax VALU).
            const ushort* cbm_h = PREC ? (cbm + ((size_t)(b & 63)*12 + h)*2401) : (const ushort*)0;
            float add_[4][4];
            #pragma unroll
            for (int i = 0; i < 4; ++i){
                const int r = mt*16 + lg*4 + i;
                const int rbase = r * NTOK;
                #pragma unroll
                for (int nt = 0; nt < 4; ++nt){
                    int j = nt*16 + l15;
                    bool ok = (r < NTOK) && (j < NTOK);
                    int o = ok ? (rbase + j) : 0;
                    float add;
                    if (PREC) add = bf2f(cbm_h[o]);
                    else      add = bf2f(lbt[(int)lidx[o]*12 + h]) + bf2f(lmask[o]);
                    add_[i][nt] = ok ? add : -13000.0f;
                }
            }
            // Hoist proj B-frags for this pass (used after the barrier below;
            // issued here they complete long before the barrier's vmcnt drain).
            s16x8 pw[2][3];
            #pragma unroll
            for (int hh2 = 0; hh2 < 2; ++hh2){
                const int h2 = h0 + 2*p + hh2;
                #pragma unroll
                for (int nt = 0; nt < 3; ++nt){
                    if (PREW){
                        pw[hh2][nt] = *(const s16x8*)(wp_pre + ((size_t)(h2*24 + wave*3 + nt)*64 + lane)*8);
                    } else {
                        #pragma unroll
                        for (int i = 0; i < 8; ++i)
                            pw[hh2][nt][i] = (short)f2bf(proj_w[(size_t)(h2*32 + lg*8 + i)*384 + (wave*3 + nt)*16 + l15]);
                    }
                }
            }

            // scores = q @ k^T  (hd = 32, single K-step)
            f32x4 sc[4];
            {
                s16x8 aq = *(const s16x8*)(lq + (hh*MROWS + mt*16 + l15)*QK_STR + lg*8);
                #pragma unroll
                for (int nt = 0; nt < 4; ++nt){
                    s16x8 bk = *(const s16x8*)(lk + (hh*MROWS + nt*16 + l15)*QK_STR + lg*8);
                    sc[nt] = __builtin_amdgcn_mfma_f32_16x16x32_bf16(aq, bk, zf, 0, 0, 0);
                }
            }
            // softmax per row across the 16-lane group. No max-subtraction:
            // softmax is shift-invariant and scores are O(1) by construction
            // (|s| <= ~14 worst-tail vs exp overflow at 88); masked/padded
            // entries exp to 0; padded rows give exact-0 P rows (0 * inv).
            #pragma unroll
            for (int i = 0; i < 4; ++i){
                const int r = mt*16 + lg*4 + i;
                float e0 = __expf(sc[0][i] + add_[i][0]);
                float e1 = __expf(sc[1][i] + add_[i][1]);
                float e2 = __expf(sc[2][i] + add_[i][2]);
                float e3 = __expf(sc[3][i] + add_[i][3]);
                float sm = (e0 + e1) + (e2 + e3);
                sm += __shfl_xor(sm, 1);
                sm += __shfl_xor(sm, 2);
                sm += __shfl_xor(sm, 4);
                sm += __shfl_xor(sm, 8);
                float inv = 1.0f / (sm + 1e-30f);
                ushort* pr = lps + (wg*MROWS + r)*PS_STR;
                pr[     l15] = f2bf(e0*inv);
                pr[16 + l15] = f2bf(e1*inv);
                pr[32 + l15] = f2bf(e2*inv);
                pr[48 + l15] = f2bf(e3*inv);
            }

            // PV: wave-private lps -> no barrier needed
            f32x4 oa[2]; oa[0] = zf; oa[1] = zf;
            #pragma unroll
            for (int kk = 0; kk < 2; ++kk){
                s16x8 ap = *(const s16x8*)(lps + (wg*MROWS + mt*16 + l15)*PS_STR + kk*32 + lg*8);
                #pragma unroll
                for (int nt = 0; nt < 2; ++nt){
                    s16x8 bv = *(const s16x8*)(lvt + (hh*32 + nt*16 + l15)*VT_STR + kk*32 + lg*8);
                    oa[nt] = __builtin_amdgcn_mfma_f32_16x16x32_bf16(ap, bv, oa[nt], 0, 0, 0);
                }
            }
            ushort* lohb = loh + (size_t)((p & 1)*2)*MROWS*OH_STR;
            #pragma unroll
            for (int nt = 0; nt < 2; ++nt)
                #pragma unroll
                for (int i = 0; i < 4; ++i){
                    int r = mt*16 + lg*4 + i;
                    lohb[(wg*MROWS + r)*OH_STR + nt*16 + l15] = f2bf(oa[nt][i]);
                }
            __syncthreads();

            // proj partial: B-frags already in pw, each loh A-frag read once
            #pragma unroll
            for (int hh2 = 0; hh2 < 2; ++hh2){
                #pragma unroll
                for (int m = 0; m < 4; ++m){
                    s16x8 a = *(const s16x8*)(lohb + (hh2*MROWS + m*16 + l15)*OH_STR + lg*8);
                    #pragma unroll
                    for (int nt = 0; nt < 3; ++nt)
                        oacc[m][nt] = __builtin_amdgcn_mfma_f32_16x16x32_bf16(a, pw[hh2][nt], oacc[m][nt], 0, 0, 0);
                }
            }
            // no second barrier: loh double-buffered, lps wave-private; the
            // next write to this loh buffer is >=2 barriers away.
        }
    }

    // ---- epilogue: += proj_b, store fp32
    #pragma unroll
    for (int n = 0; n < 3; ++n){
        const int col = wave*48 + n*16 + l15;
        const float pb = proj_b[col];
        #pragma unroll
        for (int m = 0; m < 4; ++m)
            #pragma unroll
            for (int i = 0; i < 4; ++i){
                int r = m*16 + lg*4 + i;
                if (r < NTOK)
                    out[((size_t)b*NTOK + r)*DIM_ + col] = oacc[m][n][i] + pb;
            }
    }
}

extern "C" void kernel_launch(void* const* d_in, const int* in_sizes, int n_in,
                              void* d_out, int out_size, void* d_ws, size_t ws_size,
                              hipStream_t stream)
{
    const float* x          = (const float*)d_in[0];
    const float* mask       = (const float*)d_in[1];
    const float* qkv_w      = (const float*)d_in[2];
    const float* qkv_b      = (const float*)d_in[3];
    const float* proj_w     = (const float*)d_in[4];
    const float* proj_b     = (const float*)d_in[5];
    const float* bias_table = (const float*)d_in[6];
    const int*   rel_index  = (const int*)d_in[7];
    float* out = (float*)d_out;

    // Raise the dynamic-LDS cap in case the runtime enforces the 64 KB
    // default. Host-side, idempotent, errors ignored (no-op where the launch
    // would already succeed). Not stream-ordered -> graph-capture-safe.
    (void)hipFuncSetAttribute((const void*)&win_attn_kernel<true, true>,
                              hipFuncAttributeMaxDynamicSharedMemorySize, SMEM_SMALL);
    (void)hipFuncSetAttribute((const void*)&win_attn_kernel<true, false>,
                              hipFuncAttributeMaxDynamicSharedMemorySize, SMEM_BIG);
    (void)hipFuncSetAttribute((const void*)&win_attn_kernel<false, false>,
                              hipFuncAttributeMaxDynamicSharedMemorySize, SMEM_BIG);

    const bool prew = (d_ws != nullptr) && (ws_size >= WS_W);
    const bool prec = (d_ws != nullptr) && (ws_size >= WS_FULL);

    ushort* wq  = (ushort*)d_ws;
    ushort* wp  = wq + QKV_PRE_ELEMS;
    ushort* cbm = wp + PROJ_PRE_ELEMS;

    if (prew){
        const int totalw = QKV_PRE_ELEMS + PROJ_PRE_ELEMS;
        prep_weights<<<(totalw + 255)/256, 256, 0, stream>>>(qkv_w, proj_w, wq, wp);
    }
    if (prec){
        prep_cbm<<<(CBM_ELEMS + 255)/256, 256, 0, stream>>>(mask, bias_table, rel_index, cbm);
        win_attn_kernel<true, true><<<4096, 512, SMEM_SMALL, stream>>>(
            x, mask, qkv_b, bias_table, rel_index, proj_b,
            wq, wp, cbm, qkv_w, proj_w, out);
    } else if (prew){
        win_attn_kernel<true, false><<<4096, 512, SMEM_BIG, stream>>>(
            x, mask, qkv_b, bias_table, rel_index, proj_b,
            wq, wp, nullptr, qkv_w, proj_w, out);
    } else {
        win_attn_kernel<false, false><<<4096, 512, SMEM_BIG, stream>>>(
            x, mask, qkv_b, bias_table, rel_index, proj_b,
            nullptr, nullptr, nullptr, qkv_w, proj_w, out);
    }
}